// Round 7
// baseline (187.882 us; speedup 1.0000x reference)
//
#include <hip/hip_runtime.h>
#include <hip/hip_bf16.h>

typedef __attribute__((ext_vector_type(8))) short short8_t;
typedef __attribute__((ext_vector_type(4))) float f32x4;

#define NB 2
#define CC 64
#define RCC 8
#define NN 9216
#define QT 64
#define QTILES 144          // NN/QT
#define PPART_B 8448        // bytes/partial: [64q][64ch] bf16 O + 64 f32 rowsums

static __device__ __forceinline__ unsigned short f2bf(float f) {
    unsigned int u = __builtin_bit_cast(unsigned int, f);
    u += 0x7fffu + ((u >> 16) & 1u);
    return (unsigned short)(u >> 16);
}
static __device__ __forceinline__ unsigned int cvt_pk_bf16(float lo, float hi) {
    unsigned int r;
    asm("v_cvt_pk_bf16_f32 %0, %1, %2" : "=v"(r) : "v"(lo), "v"(hi));
    return r;
}

// ---------------- projection kernel ----------------
// grid = (B*N/256, 2), 256 threads. y=0: q + v[0:32); y=1: k + v[32:64).
// q scale folds 1/sqrt(N), log2(e), and 1/4 (replicate-x4 MFMA trick).
// V stored kslot-PERMUTED within each aligned 32-key group:
//   pos 8g+s (s=0..3) holds key 4g+s; pos 8g+4+s holds key 16+4g+s
__global__ __launch_bounds__(256) void proj_kernel(
    const float* __restrict__ x,
    const float* __restrict__ wq, const float* __restrict__ bq,
    const float* __restrict__ wk, const float* __restrict__ bk,
    const float* __restrict__ wv, const float* __restrict__ bv,
    unsigned short* __restrict__ qbf,   // [B][N][8] bf16
    unsigned short* __restrict__ kbf,   // [B][N][8] bf16
    unsigned short* __restrict__ vbf)   // [B][C][N] bf16, permuted
{
    const int grp = blockIdx.y;
    __shared__ float sw[40 * CC];
    __shared__ float sb[40];
    const int t = threadIdx.x;

    const float* w8 = grp ? wk : wq;
    const float* b8 = grp ? bk : bq;
    for (int i = t; i < 8 * CC; i += 256) sw[i] = w8[i];
    for (int i = t; i < 32 * CC; i += 256) sw[8 * CC + i] = wv[grp * 32 * CC + i];
    if (t < 8) sb[t] = b8[t];
    else if (t < 40) sb[t] = bv[grp * 32 + (t - 8)];
    __syncthreads();

    const int gid = blockIdx.x * 256 + t;    // 0 .. B*N-1 exact
    const int b = gid / NN, n = gid % NN;
    const float* xp = x + (size_t)b * CC * NN + n;
    float xv[CC];
    #pragma unroll
    for (int c = 0; c < CC; ++c) xv[c] = xp[(size_t)c * NN];

    const float scale = grp ? 1.0f : 0.0037570183356483423f; // log2e/(96*4)
    unsigned short* dst = grp ? kbf : qbf;
    union { unsigned short u[8]; uint4 q4; } pk;
    #pragma unroll
    for (int r = 0; r < RCC; ++r) {
        const float4* wr = (const float4*)&sw[r * CC];
        float a = sb[r];
        #pragma unroll
        for (int c4 = 0; c4 < CC / 4; ++c4) {
            float4 wd = wr[c4];
            a += wd.x * xv[4*c4] + wd.y * xv[4*c4+1] + wd.z * xv[4*c4+2] + wd.w * xv[4*c4+3];
        }
        pk.u[r] = f2bf(a * scale);
    }
    *(uint4*)(dst + (size_t)gid * RCC) = pk.q4;

    // kslot-permuted V position
    const int n32 = n & 31;
    const int np = (n & ~31) | ((n32 & 12) << 1) | (n32 & 3) | ((n32 >> 2) & 4);
    for (int o = 0; o < 32; ++o) {
        const float4* wr = (const float4*)&sw[(8 + o) * CC];
        float a = sb[8 + o];
        #pragma unroll
        for (int c4 = 0; c4 < CC / 4; ++c4) {
            float4 wd = wr[c4];
            a += wd.x * xv[4*c4] + wd.y * xv[4*c4+1] + wd.z * xv[4*c4+2] + wd.w * xv[4*c4+3];
        }
        vbf[((size_t)b * CC + grp * 32 + o) * NN + np] = f2bf(a);
    }
}

// ---------------- attention kernel ----------------
// grid = NB*QTILES*WSPL blocks of ONE wave (64 thr). No LDS, no barriers.
// Wave: (b, 64 queries, key-slice of NN/WSPL keys), all 64 channels,
// 32-key chunks, 2-deep register pipeline. Rowsum in VALU (frees matrix pipe).
#define LOADC(k0v, K0, K1, V0, V1, V2, V3) do {                              \
    K0 = *(const short8_t*)(kp + (size_t)((k0v) + li) * RCC);                \
    K1 = *(const short8_t*)(kp + (size_t)((k0v) + 16 + li) * RCC);           \
    V0 = *(const short8_t*)(vr0 + (k0v) + vo);                               \
    V1 = *(const short8_t*)(vr1 + (k0v) + vo);                               \
    V2 = *(const short8_t*)(vr2 + (k0v) + vo);                               \
    V3 = *(const short8_t*)(vr3 + (k0v) + vo);                               \
} while (0)

#define COMPUTE(K0, K1, V0, V1, V2, V3) do {                                 \
    __builtin_amdgcn_s_setprio(1);                                           \
    _Pragma("unroll")                                                        \
    for (int j = 0; j < 4; ++j) {                                            \
        f32x4 s0 = __builtin_amdgcn_mfma_f32_16x16x32_bf16(K0, qf[j], zero4, 0, 0, 0); \
        f32x4 s1 = __builtin_amdgcn_mfma_f32_16x16x32_bf16(K1, qf[j], zero4, 0, 0, 0); \
        float p0 = __builtin_amdgcn_exp2f(s0[0]);                            \
        float p1 = __builtin_amdgcn_exp2f(s0[1]);                            \
        float p2 = __builtin_amdgcn_exp2f(s0[2]);                            \
        float p3 = __builtin_amdgcn_exp2f(s0[3]);                            \
        float p4 = __builtin_amdgcn_exp2f(s1[0]);                            \
        float p5 = __builtin_amdgcn_exp2f(s1[1]);                            \
        float p6 = __builtin_amdgcn_exp2f(s1[2]);                            \
        float p7 = __builtin_amdgcn_exp2f(s1[3]);                            \
        rs[j] += ((p0 + p1) + (p2 + p3)) + ((p4 + p5) + (p6 + p7));          \
        union { unsigned int u[4]; short8_t v; } pw;                         \
        pw.u[0] = cvt_pk_bf16(p0, p1);                                       \
        pw.u[1] = cvt_pk_bf16(p2, p3);                                       \
        pw.u[2] = cvt_pk_bf16(p4, p5);                                       \
        pw.u[3] = cvt_pk_bf16(p6, p7);                                       \
        const short8_t pb = pw.v;                                            \
        acc[0][j] = __builtin_amdgcn_mfma_f32_16x16x32_bf16(V0, pb, acc[0][j], 0, 0, 0); \
        acc[1][j] = __builtin_amdgcn_mfma_f32_16x16x32_bf16(V1, pb, acc[1][j], 0, 0, 0); \
        acc[2][j] = __builtin_amdgcn_mfma_f32_16x16x32_bf16(V2, pb, acc[2][j], 0, 0, 0); \
        acc[3][j] = __builtin_amdgcn_mfma_f32_16x16x32_bf16(V3, pb, acc[3][j], 0, 0, 0); \
    }                                                                        \
    __builtin_amdgcn_s_setprio(0);                                           \
} while (0)

template<int WSPL>
__global__ __launch_bounds__(64, 3) void attn_kernel(
    const unsigned short* __restrict__ qbf,
    const unsigned short* __restrict__ kbf,
    const unsigned short* __restrict__ vbf,
    char* __restrict__ pbuf)
{
    constexpr int KPW = NN / WSPL;       // keys per wave
    constexpr int NCH = KPW / 32;        // 32-key chunks
    static_assert(NCH % 2 == 0, "even NCH for 2-deep pipeline");

    const int l = threadIdx.x;
    const int g = l >> 4, li = l & 15;

    const int bid = blockIdx.x;
    const int ws = bid % WSPL;
    const int qt = (bid / WSPL) % QTILES;
    const int b  = bid / (WSPL * QTILES);
    const int qbase = qt * QT;
    const int key_base = ws * KPW;

    const unsigned short* qb = qbf + (size_t)b * NN * RCC;
    const unsigned short* kp = kbf + (size_t)b * NN * RCC;
    const unsigned short* vb = vbf + (size_t)b * CC * NN;
    const unsigned short* vr0 = vb + (size_t)li * NN;
    const unsigned short* vr1 = vb + (size_t)(16 + li) * NN;
    const unsigned short* vr2 = vb + (size_t)(32 + li) * NN;
    const unsigned short* vr3 = vb + (size_t)(48 + li) * NN;
    const int vo = 8 * g;

    short8_t qf[4];
    #pragma unroll
    for (int j = 0; j < 4; ++j)
        qf[j] = *(const short8_t*)(qb + (size_t)(qbase + 16 * j + li) * RCC);

    const f32x4 zero4 = {0.f, 0.f, 0.f, 0.f};
    f32x4 acc[4][4];    // [f = ch/16][j = q/16]
    #pragma unroll
    for (int f = 0; f < 4; ++f)
        #pragma unroll
        for (int j = 0; j < 4; ++j) acc[f][j] = zero4;
    float rs[4] = {0.f, 0.f, 0.f, 0.f};

    short8_t kA0, kA1, vA0, vA1, vA2, vA3;
    short8_t kB0, kB1, vB0, vB1, vB2, vB3;

    int k0 = key_base;
    LOADC(k0, kA0, kA1, vA0, vA1, vA2, vA3);
    for (int c = 0; c < NCH; c += 2) {
        LOADC(k0 + 32, kB0, kB1, vB0, vB1, vB2, vB3);
        COMPUTE(kA0, kA1, vA0, vA1, vA2, vA3);
        if (c + 2 < NCH)
            LOADC(k0 + 64, kA0, kA1, vA0, vA1, vA2, vA3);
        COMPUTE(kB0, kB1, vB0, vB1, vB2, vB3);
        k0 += 64;
    }

    // ---- rowsum reduce across lane-groups (all lanes end with full sum) ----
    #pragma unroll
    for (int j = 0; j < 4; ++j) {
        rs[j] += __shfl_xor(rs[j], 16, 64);
        rs[j] += __shfl_xor(rs[j], 32, 64);
    }

    // ---- write bf16 partial O ([q][ch]) + f32 rowsums ----
    unsigned short* po = (unsigned short*)(pbuf + (size_t)bid * PPART_B);
    #pragma unroll
    for (int j = 0; j < 4; ++j) {
        #pragma unroll
        for (int f = 0; f < 4; ++f) {
            uint2 d;
            d.x = cvt_pk_bf16(acc[f][j][0], acc[f][j][1]);
            d.y = cvt_pk_bf16(acc[f][j][2], acc[f][j][3]);
            *(uint2*)(po + (size_t)(16 * j + li) * CC + 16 * f + 4 * g) = d;
        }
    }
    if (g == 0) {
        float* prs = (float*)(pbuf + (size_t)bid * PPART_B + 8192);
        #pragma unroll
        for (int j = 0; j < 4; ++j) prs[16 * j + li] = rs[j];
    }
}

// ---------------- combine kernel ----------------
// grid = NB*QTILES, 256 threads: thread t -> query q = t&63, ch group t>>6.
template<int WSPL>
__global__ __launch_bounds__(256) void combine_kernel(
    const char* __restrict__ pbuf,
    const float* __restrict__ x,
    const float* __restrict__ gamma,
    float* __restrict__ out)
{
    const int bid = blockIdx.x;             // b*QTILES + qt
    const int b = bid / QTILES, qt = bid % QTILES;
    const char* pc = pbuf + (size_t)bid * WSPL * PPART_B;
    const int t = threadIdx.x;
    const int q = t & 63, cg = t >> 6;

    float den = 0.f;
    #pragma unroll
    for (int s = 0; s < WSPL; ++s)
        den += *(const float*)(pc + (size_t)s * PPART_B + 8192 + 4 * q);
    const float inv = 1.0f / den;
    const float gm = gamma[0];

    float o[16];
    #pragma unroll
    for (int i = 0; i < 16; ++i) o[i] = 0.f;
    #pragma unroll
    for (int s = 0; s < WSPL; ++s) {
        const unsigned int* dp = (const unsigned int*)(pc + (size_t)s * PPART_B + (size_t)(q * CC + cg * 16) * 2);
        #pragma unroll
        for (int d = 0; d < 8; ++d) {
            unsigned int u = dp[d];
            o[2 * d]     += __builtin_bit_cast(float, u << 16);
            o[2 * d + 1] += __builtin_bit_cast(float, u & 0xffff0000u);
        }
    }
    #pragma unroll
    for (int i = 0; i < 16; ++i) {
        const int ch = cg * 16 + i;
        const size_t i0 = ((size_t)b * CC + ch) * NN + (size_t)qt * QT + q;
        out[i0] = x[i0] + gm * o[i] * inv;
    }
}

extern "C" void kernel_launch(void* const* d_in, const int* in_sizes, int n_in,
                              void* d_out, int out_size, void* d_ws, size_t ws_size,
                              hipStream_t stream) {
    const float* x     = (const float*)d_in[0];
    const float* wq    = (const float*)d_in[1];
    const float* bq    = (const float*)d_in[2];
    const float* wk    = (const float*)d_in[3];
    const float* bk    = (const float*)d_in[4];
    const float* wv    = (const float*)d_in[5];
    const float* bv    = (const float*)d_in[6];
    const float* gamma = (const float*)d_in[7];
    float* out = (float*)d_out;

    unsigned short* qbf = (unsigned short*)d_ws;
    unsigned short* kbf = qbf + (size_t)NB * NN * RCC;
    unsigned short* vbf = kbf + (size_t)NB * NN * RCC;
    size_t bufbytes = ((size_t)2 * NB * NN * RCC + (size_t)NB * CC * NN) * sizeof(unsigned short);
    size_t poff = (bufbytes + 255) & ~(size_t)255;
    char* pbuf = (char*)d_ws + poff;
    size_t avail = ws_size > poff ? ws_size - poff : 0;

    proj_kernel<<<dim3((NB * NN) / 256, 2), 256, 0, stream>>>(
        x, wq, bq, wk, bk, wv, bv, qbf, kbf, vbf);

    auto fits = [&](int wspl) {
        return avail >= (size_t)NB * QTILES * wspl * PPART_B;
    };

    if (fits(24)) {
        attn_kernel<24><<<NB * QTILES * 24, 64, 0, stream>>>(qbf, kbf, vbf, pbuf);
        combine_kernel<24><<<NB * QTILES, 256, 0, stream>>>(pbuf, x, gamma, out);
    } else if (fits(16)) {
        attn_kernel<16><<<NB * QTILES * 16, 64, 0, stream>>>(qbf, kbf, vbf, pbuf);
        combine_kernel<16><<<NB * QTILES, 256, 0, stream>>>(pbuf, x, gamma, out);
    } else if (fits(12)) {
        attn_kernel<12><<<NB * QTILES * 12, 64, 0, stream>>>(qbf, kbf, vbf, pbuf);
        combine_kernel<12><<<NB * QTILES, 256, 0, stream>>>(pbuf, x, gamma, out);
    } else {
        attn_kernel<8><<<NB * QTILES * 8, 64, 0, stream>>>(qbf, kbf, vbf, pbuf);
        combine_kernel<8><<<NB * QTILES, 256, 0, stream>>>(pbuf, x, gamma, out);
    }
}

// Round 8
// 93.094 us; speedup vs baseline: 2.0182x; 2.0182x over previous
//
#include <hip/hip_runtime.h>
#include <hip/hip_bf16.h>

typedef __attribute__((ext_vector_type(8))) short short8_t;
typedef __attribute__((ext_vector_type(16))) float f32x16;

#define NB 2
#define CC 64
#define RCC 8
#define NN 9216
#define QT 64
#define QTILES 144          // NN/QT
#define PPART_B 8448        // bytes/partial: [64ch][64q] bf16 O + 64 f32 rowsums

static __device__ __forceinline__ unsigned short f2bf(float f) {
    unsigned int u = __builtin_bit_cast(unsigned int, f);
    u += 0x7fffu + ((u >> 16) & 1u);
    return (unsigned short)(u >> 16);
}
static __device__ __forceinline__ unsigned int cvt_pk_bf16(float lo, float hi) {
    unsigned int r;
    asm("v_cvt_pk_bf16_f32 %0, %1, %2" : "=v"(r) : "v"(lo), "v"(hi));
    return r;
}

// ---------------- projection kernel ----------------
// grid = (B*N/256, 2), 256 threads. y=0: q + v[0:32); y=1: k + v[32:64).
// q scale folds 1/sqrt(N), log2(e), and 1/2 (replicate-x2 over 32x32x16 kdim).
// V stored with key bits 2<->3 swapped within each aligned 32-key group, so
// attn's PV A-fragment (32x32x16 kslot order) is one contiguous 16B load.
__global__ __launch_bounds__(256) void proj_kernel(
    const float* __restrict__ x,
    const float* __restrict__ wq, const float* __restrict__ bq,
    const float* __restrict__ wk, const float* __restrict__ bk,
    const float* __restrict__ wv, const float* __restrict__ bv,
    unsigned short* __restrict__ qbf,   // [B][N][8] bf16
    unsigned short* __restrict__ kbf,   // [B][N][8] bf16
    unsigned short* __restrict__ vbf)   // [B][C][N] bf16, bit-swapped
{
    const int grp = blockIdx.y;
    __shared__ float sw[40 * CC];
    __shared__ float sb[40];
    const int t = threadIdx.x;

    const float* w8 = grp ? wk : wq;
    const float* b8 = grp ? bk : bq;
    for (int i = t; i < 8 * CC; i += 256) sw[i] = w8[i];
    for (int i = t; i < 32 * CC; i += 256) sw[8 * CC + i] = wv[grp * 32 * CC + i];
    if (t < 8) sb[t] = b8[t];
    else if (t < 40) sb[t] = bv[grp * 32 + (t - 8)];
    __syncthreads();

    const int gid = blockIdx.x * 256 + t;    // 0 .. B*N-1 exact
    const int b = gid / NN, n = gid % NN;
    const float* xp = x + (size_t)b * CC * NN + n;
    float xv[CC];
    #pragma unroll
    for (int c = 0; c < CC; ++c) xv[c] = xp[(size_t)c * NN];

    const float scale = grp ? 1.0f : 0.0075140366685186738f; // log2e/(96*2)
    unsigned short* dst = grp ? kbf : qbf;
    union { unsigned short u[8]; uint4 q4; } pk;
    #pragma unroll
    for (int r = 0; r < RCC; ++r) {
        const float4* wr = (const float4*)&sw[r * CC];
        float a = sb[r];
        #pragma unroll
        for (int c4 = 0; c4 < CC / 4; ++c4) {
            float4 wd = wr[c4];
            a += wd.x * xv[4*c4] + wd.y * xv[4*c4+1] + wd.z * xv[4*c4+2] + wd.w * xv[4*c4+3];
        }
        pk.u[r] = f2bf(a * scale);
    }
    *(uint4*)(dst + (size_t)gid * RCC) = pk.q4;

    // V position: swap bits 2 and 3 of n (within aligned 32-group)
    const int np = (n & ~12) | ((n & 4) << 1) | ((n & 8) >> 1);
    for (int o = 0; o < 32; ++o) {
        const float4* wr = (const float4*)&sw[(8 + o) * CC];
        float a = sb[8 + o];
        #pragma unroll
        for (int c4 = 0; c4 < CC / 4; ++c4) {
            float4 wd = wr[c4];
            a += wd.x * xv[4*c4] + wd.y * xv[4*c4+1] + wd.z * xv[4*c4+2] + wd.w * xv[4*c4+3];
        }
        vbf[((size_t)b * CC + grp * 32 + o) * NN + np] = f2bf(a);
    }
}

// ---------------- attention kernel ----------------
// grid = NB*QTILES*KSPL (ks fastest), 256 threads = 4 waves.
// Wave w: keys [key_base, key_base+KPW), all 64 ch, 64 q, 32-key chunks.
// 32x32x16 MFMA throughout; S' regs ARE the PV B-fragments (key bit2<->3
// permutation matches V's stored layout). No LDS in main loop.
#define LOADC(k0v, KA, V00, V01, V10, V11) do {                              \
    KA  = *(const short8_t*)(kp + (size_t)((k0v) + l31) * RCC);              \
    V00 = *(const short8_t*)(vr0 + (k0v) + vo);                              \
    V01 = *(const short8_t*)(vr0 + (k0v) + 16 + vo);                         \
    V10 = *(const short8_t*)(vr1 + (k0v) + vo);                              \
    V11 = *(const short8_t*)(vr1 + (k0v) + 16 + vo);                         \
} while (0)

#define PROC(S, QH, V00, V01, V10, V11) do {                                 \
    float p0  = __builtin_amdgcn_exp2f(S[0]);                                \
    float p1  = __builtin_amdgcn_exp2f(S[1]);                                \
    float p2  = __builtin_amdgcn_exp2f(S[2]);                                \
    float p3  = __builtin_amdgcn_exp2f(S[3]);                                \
    float p4  = __builtin_amdgcn_exp2f(S[4]);                                \
    float p5  = __builtin_amdgcn_exp2f(S[5]);                                \
    float p6  = __builtin_amdgcn_exp2f(S[6]);                                \
    float p7  = __builtin_amdgcn_exp2f(S[7]);                                \
    float p8  = __builtin_amdgcn_exp2f(S[8]);                                \
    float p9  = __builtin_amdgcn_exp2f(S[9]);                                \
    float p10 = __builtin_amdgcn_exp2f(S[10]);                               \
    float p11 = __builtin_amdgcn_exp2f(S[11]);                               \
    float p12 = __builtin_amdgcn_exp2f(S[12]);                               \
    float p13 = __builtin_amdgcn_exp2f(S[13]);                               \
    float p14 = __builtin_amdgcn_exp2f(S[14]);                               \
    float p15 = __builtin_amdgcn_exp2f(S[15]);                               \
    rs[QH] += (((p0+p1)+(p2+p3))+((p4+p5)+(p6+p7)))                          \
            + (((p8+p9)+(p10+p11))+((p12+p13)+(p14+p15)));                   \
    union { unsigned int u[4]; short8_t v; } w0_, w1_;                       \
    w0_.u[0] = cvt_pk_bf16(p0, p1);   w0_.u[1] = cvt_pk_bf16(p2, p3);        \
    w0_.u[2] = cvt_pk_bf16(p4, p5);   w0_.u[3] = cvt_pk_bf16(p6, p7);        \
    w1_.u[0] = cvt_pk_bf16(p8, p9);   w1_.u[1] = cvt_pk_bf16(p10, p11);      \
    w1_.u[2] = cvt_pk_bf16(p12, p13); w1_.u[3] = cvt_pk_bf16(p14, p15);      \
    acc[0][QH] = __builtin_amdgcn_mfma_f32_32x32x16_bf16(V00, w0_.v, acc[0][QH], 0, 0, 0); \
    acc[1][QH] = __builtin_amdgcn_mfma_f32_32x32x16_bf16(V10, w0_.v, acc[1][QH], 0, 0, 0); \
    acc[0][QH] = __builtin_amdgcn_mfma_f32_32x32x16_bf16(V01, w1_.v, acc[0][QH], 0, 0, 0); \
    acc[1][QH] = __builtin_amdgcn_mfma_f32_32x32x16_bf16(V11, w1_.v, acc[1][QH], 0, 0, 0); \
} while (0)

#define COMPUTE(KA, V00, V01, V10, V11) do {                                 \
    __builtin_amdgcn_s_setprio(1);                                           \
    f32x16 s0 = __builtin_amdgcn_mfma_f32_32x32x16_bf16(KA, qf0, zero16, 0, 0, 0); \
    f32x16 s1 = __builtin_amdgcn_mfma_f32_32x32x16_bf16(KA, qf1, zero16, 0, 0, 0); \
    PROC(s0, 0, V00, V01, V10, V11);                                         \
    PROC(s1, 1, V00, V01, V10, V11);                                         \
    __builtin_amdgcn_s_setprio(0);                                           \
} while (0)

template<int KSPL>
__global__ __launch_bounds__(256, 3) void attn_kernel(
    const unsigned short* __restrict__ qbf,
    const unsigned short* __restrict__ kbf,
    const unsigned short* __restrict__ vbf,
    char* __restrict__ pbuf)
{
    constexpr int KPB = NN / KSPL;
    constexpr int KPW = KPB / 4;
    constexpr int NCH = KPW / 32;
    static_assert(NCH % 2 == 0, "even NCH for 2-deep pipeline");
    __shared__ char smem[17920];   // epilogue: 4 x [32][33] f32 sO + [4][64] rsum

    const int tid = threadIdx.x;
    const int w = tid >> 6, l = tid & 63;
    const int l31 = l & 31, h = l >> 5;

    const int bid = blockIdx.x;
    const int ks = bid % KSPL;
    const int qt = (bid / KSPL) % QTILES;
    const int b  = bid / (KSPL * QTILES);
    const int qbase = qt * QT;
    const int key_base = ks * KPB + w * KPW;

    const unsigned short* qb = qbf + (size_t)b * NN * RCC;
    const unsigned short* kp = kbf + (size_t)b * NN * RCC;
    const unsigned short* vb = vbf + (size_t)b * CC * NN;
    const unsigned short* vr0 = vb + (size_t)l31 * NN;
    const unsigned short* vr1 = vb + (size_t)(32 + l31) * NN;
    const int vo = 8 * h;

    const short8_t qf0 = *(const short8_t*)(qb + (size_t)(qbase + l31) * RCC);
    const short8_t qf1 = *(const short8_t*)(qb + (size_t)(qbase + 32 + l31) * RCC);

    const f32x16 zero16 = {0,0,0,0,0,0,0,0,0,0,0,0,0,0,0,0};
    f32x16 acc[2][2];   // [c2 = ch/32][qh = q/32]
    acc[0][0] = zero16; acc[0][1] = zero16; acc[1][0] = zero16; acc[1][1] = zero16;
    float rs[2] = {0.f, 0.f};

    short8_t kA, vA00, vA01, vA10, vA11;
    short8_t kB, vB00, vB01, vB10, vB11;

    int k0 = key_base;
    LOADC(k0, kA, vA00, vA01, vA10, vA11);
    for (int c = 0; c < NCH; c += 2) {
        LOADC(k0 + 32, kB, vB00, vB01, vB10, vB11);
        COMPUTE(kA, vA00, vA01, vA10, vA11);
        if (c + 2 < NCH)
            LOADC(k0 + 64, kA, vA00, vA01, vA10, vA11);
        COMPUTE(kB, vB00, vB01, vB10, vB11);
        k0 += 64;
    }

    // rowsum: reduce over h halves (keys split by h within each chunk)
    rs[0] += __shfl_xor(rs[0], 32, 64);
    rs[1] += __shfl_xor(rs[1], 32, 64);

    float* sO   = (float*)smem;                 // 4 regions x [32][33] f32
    float* rsum = (float*)(smem + 16896);       // [4][64]
    if (h == 0) {
        rsum[w * 64 + l31]      = rs[0];
        rsum[w * 64 + 32 + l31] = rs[1];
    }

    // ---- cross-wave O reduce: 4 rounds of slice rotation ----
    float accR[16];
    #pragma unroll
    for (int r = 0; r < 16; ++r) accR[r] = 0.f;

    #pragma unroll
    for (int rr = 0; rr < 4; ++rr) {
        const int s = (w + rr) & 3;
        __syncthreads();
        switch (s) {
#define WR_SLICE(S) \
            { _Pragma("unroll") \
              for (int r = 0; r < 16; ++r) \
                  sO[(S) * 1056 + ((r & 3) + 8 * (r >> 2) + 4 * h) * 33 + l31] = acc[(S) >> 1][(S) & 1][r]; }
            case 0: WR_SLICE(0); break;
            case 1: WR_SLICE(1); break;
            case 2: WR_SLICE(2); break;
            case 3: WR_SLICE(3); break;
#undef WR_SLICE
        }
        __syncthreads();
        #pragma unroll
        for (int r = 0; r < 16; ++r)
            accR[r] += sO[w * 1056 + ((r & 3) + 8 * (r >> 2) + 4 * h) * 33 + l31];
    }

    // ---- write bf16 partial O ([ch][q], coalesced 2B stores) + rowsums ----
    unsigned short* po = (unsigned short*)(pbuf + (size_t)bid * PPART_B);
    const int c2 = w >> 1, qh = w & 1;
    #pragma unroll
    for (int r = 0; r < 16; ++r) {
        const int ch = c2 * 32 + (r & 3) + 8 * (r >> 2) + 4 * h;
        po[ch * QT + 32 * qh + l31] = f2bf(accR[r]);
    }
    if (tid < QT) {
        float* prs = (float*)(pbuf + (size_t)bid * PPART_B + 8192);
        prs[tid] = rsum[tid] + rsum[64 + tid] + rsum[128 + tid] + rsum[192 + tid];
    }
}

// ---------------- combine kernel ----------------
// partial format: [64 ch][64 q] bf16 + 64 f32 rowsums. Coalesced u32 reads.
template<int KSPL>
__global__ __launch_bounds__(256) void combine_kernel(
    const char* __restrict__ pbuf,
    const float* __restrict__ x,
    const float* __restrict__ gamma,
    float* __restrict__ out)
{
    const int bid = blockIdx.x;             // b*QTILES + qt
    const int b = bid / QTILES, qt = bid % QTILES;
    const char* pc = pbuf + (size_t)bid * KSPL * PPART_B;
    const int t = threadIdx.x;
    __shared__ float sden[QT];
    if (t < QT) {
        float d = 0.f;
        #pragma unroll
        for (int s = 0; s < KSPL; ++s)
            d += *(const float*)(pc + (size_t)s * PPART_B + 8192 + 4 * t);
        sden[t] = 1.0f / d;
    }
    __syncthreads();
    const float gm = gamma[0];
    const int q2 = (t & 31) * 2;     // q pair
    const int chb = t >> 5;          // 0..7
    #pragma unroll
    for (int cp = 0; cp < 8; ++cp) {
        const int ch = cp * 8 + chb;
        float o0 = 0.f, o1 = 0.f;
        #pragma unroll
        for (int s = 0; s < KSPL; ++s) {
            unsigned int u = *(const unsigned int*)(pc + (size_t)s * PPART_B + (size_t)(ch * QT + q2) * 2);
            o0 += __builtin_bit_cast(float, u << 16);
            o1 += __builtin_bit_cast(float, u & 0xffff0000u);
        }
        const size_t i0 = ((size_t)b * CC + ch) * NN + (size_t)qt * QT + q2;
        float2 res;
        res.x = x[i0]     + gm * o0 * sden[q2];
        res.y = x[i0 + 1] + gm * o1 * sden[q2 + 1];
        *(float2*)(out + i0) = res;
    }
}

extern "C" void kernel_launch(void* const* d_in, const int* in_sizes, int n_in,
                              void* d_out, int out_size, void* d_ws, size_t ws_size,
                              hipStream_t stream) {
    const float* x     = (const float*)d_in[0];
    const float* wq    = (const float*)d_in[1];
    const float* bq    = (const float*)d_in[2];
    const float* wk    = (const float*)d_in[3];
    const float* bk    = (const float*)d_in[4];
    const float* wv    = (const float*)d_in[5];
    const float* bv    = (const float*)d_in[6];
    const float* gamma = (const float*)d_in[7];
    float* out = (float*)d_out;

    unsigned short* qbf = (unsigned short*)d_ws;
    unsigned short* kbf = qbf + (size_t)NB * NN * RCC;
    unsigned short* vbf = kbf + (size_t)NB * NN * RCC;
    size_t bufbytes = ((size_t)2 * NB * NN * RCC + (size_t)NB * CC * NN) * sizeof(unsigned short);
    size_t poff = (bufbytes + 255) & ~(size_t)255;
    char* pbuf = (char*)d_ws + poff;
    size_t avail = ws_size > poff ? ws_size - poff : 0;

    proj_kernel<<<dim3((NB * NN) / 256, 2), 256, 0, stream>>>(
        x, wq, bq, wk, bk, wv, bv, qbf, kbf, vbf);

    auto fits = [&](int kspl) {
        return avail >= (size_t)NB * QTILES * kspl * PPART_B;
    };

    if (fits(6)) {
        attn_kernel<6><<<NB * QTILES * 6, 256, 0, stream>>>(qbf, kbf, vbf, pbuf);
        combine_kernel<6><<<NB * QTILES, 256, 0, stream>>>(pbuf, x, gamma, out);
    } else if (fits(4)) {
        attn_kernel<4><<<NB * QTILES * 4, 256, 0, stream>>>(qbf, kbf, vbf, pbuf);
        combine_kernel<4><<<NB * QTILES, 256, 0, stream>>>(pbuf, x, gamma, out);
    } else if (fits(2)) {
        attn_kernel<2><<<NB * QTILES * 2, 256, 0, stream>>>(qbf, kbf, vbf, pbuf);
        combine_kernel<2><<<NB * QTILES, 256, 0, stream>>>(pbuf, x, gamma, out);
    } else {
        attn_kernel<1><<<NB * QTILES, 256, 0, stream>>>(qbf, kbf, vbf, pbuf);
        combine_kernel<1><<<NB * QTILES, 256, 0, stream>>>(pbuf, x, gamma, out);
    }
}